// Round 3
// baseline (112.905 us; speedup 1.0000x reference)
//
#include <hip/hip_runtime.h>
#include <math.h>

#define NPIX (8 * 256 * 256)   // B*H*W
#define CC 16                  // C
#define KK 8                   // K
#define PPT 4                  // pixels per thread
#define TPB 64                 // one wave per block

#if __has_builtin(__builtin_amdgcn_exp2f)
#define EXP2F(v) __builtin_amdgcn_exp2f(v)
#else
#define EXP2F(v) exp2f(v)
#endif
#if __has_builtin(__builtin_amdgcn_rcpf)
#define RCPF(v) __builtin_amdgcn_rcpf(v)
#else
#define RCPF(v) (1.0f / (v))
#endif

// Packed per-class constants, 160-dword stride per class k:
//   [k*160 + i*(i+1)/2 + j]  = SC * Linv[i][j]          (j<=i, 136 entries)
//   [k*160 + 136 + i]        = -SC * (Linv*mean)_i      (16 entries)
//   [k*160 + 152]            = (-8*ln(2pi) - logdet_k) * log2(e)
// where SC = sqrt(0.5*log2(e)), so prob_k = exp2(c0 - sum_i z_i^2),
// z = SC*Linv*x - SC*Linv*mean.
#define CBASE(k) ((k) * 160)
#define NCONST 1280            // 20 VGPRs * 64 lanes

// constant c lives in cv[c>>6], lane (c&63); both indices compile-time.
#define RL(c) __int_as_float(__builtin_amdgcn_readlane(__float_as_int(cv[(c) >> 6]), (c) & 63))

__global__ __launch_bounds__(TPB) void fuzzy_kernel(const float* __restrict__ x,
                                                    const float* __restrict__ mean,
                                                    const float* __restrict__ st,
                                                    float* __restrict__ out) {
    __shared__ float sq[KK][CC][CC + 1];  // unscaled tril-inverse (padded)
    __shared__ float cpk[NCONST];         // packed constant table
    const int t = threadIdx.x;            // 0..63 == lane id

    // ---- setup phase 1: columns of inv(tril(L)), 2 per thread ----
    {
        const int k = t >> 3;
        const float* L = st + k * CC * CC;
#pragma unroll
        for (int jj = 0; jj < 2; ++jj) {
            const int j = (t & 7) + jj * 8;
            float col[CC];
#pragma unroll
            for (int i = 0; i < CC; ++i) {
                float s = (i == j) ? 1.0f : 0.0f;
#pragma unroll
                for (int m = 0; m < i; ++m) s = fmaf(-L[i * CC + m], col[m], s);
                // col[m]==0 for m<j kills the invalid terms
                col[i] = (i < j) ? 0.0f : s * RCPF(L[i * CC + i]);
                sq[k][i][j] = col[i];
            }
        }
    }
    __syncthreads();

    // ---- setup phase 2: pack scaled constants; 2 rows per thread ----
    {
        const float SC = 0.8493218891f;       // sqrt(0.5*log2(e))
        const int k = t >> 3;
#pragma unroll
        for (int ii = 0; ii < 2; ++ii) {
            const int i = (t & 7) + ii * 8;
            float v = 0.0f;
#pragma unroll
            for (int j = 0; j < CC; ++j) v = fmaf(sq[k][i][j], mean[k * CC + j], v);
            cpk[CBASE(k) + 136 + i] = -v * SC;                  // negated bias
            const int tribase = CBASE(k) + i * (i + 1) / 2;
#pragma unroll
            for (int j = 0; j < CC; ++j)
                if (j <= i) cpk[tribase + j] = sq[k][i][j] * SC;
        }
        if (t < KK) {
            const float* L = st + t * CC * CC;
            float ld = 0.0f;
#pragma unroll
            for (int i = 0; i < CC; ++i) ld += __logf(fabsf(L[i * CC + i]));
            // -0.5*16*ln(2pi) = -14.7030165; log2(e) = 1.44269504
            cpk[CBASE(t) + 152] = (-14.70301653f - ld) * 1.44269504f;
        }
    }
    __syncthreads();

    // ---- distribute constants into 20 VGPRs (lane-striped) ----
    float cv[20];
#pragma unroll
    for (int q = 0; q < 20; ++q) cv[q] = cpk[q * 64 + t];   // conflict-free

    // ---- main: 4 pixels per thread, pure-VALU inner loop ----
    const size_t base = (size_t)blockIdx.x * 256 + t;       // + pp*64

    float xv[PPT][CC];
#pragma unroll
    for (int pp = 0; pp < PPT; ++pp) {
        const float4* xp = reinterpret_cast<const float4*>(x + (base + pp * 64) * CC);
#pragma unroll
        for (int q = 0; q < 4; ++q) {
            float4 v = xp[q];
            xv[pp][4 * q + 0] = v.x; xv[pp][4 * q + 1] = v.y;
            xv[pp][4 * q + 2] = v.z; xv[pp][4 * q + 3] = v.w;
        }
    }

    float pr[PPT][KK];
#pragma unroll
    for (int k = 0; k < KK; ++k) {
        float quad[PPT] = {0.0f, 0.0f, 0.0f, 0.0f};
#pragma unroll
        for (int i = 0; i < CC; ++i) {
            const float nv = RL(CBASE(k) + 136 + i);   // already negated
            float zi[PPT];
#pragma unroll
            for (int p = 0; p < PPT; ++p) zi[p] = nv;
            const int tribase = CBASE(k) + i * (i + 1) / 2;
#pragma unroll
            for (int j = 0; j <= i; ++j) {
                const float w = RL(tribase + j);
#pragma unroll
                for (int p = 0; p < PPT; ++p) zi[p] = fmaf(w, xv[p][j], zi[p]);
            }
#pragma unroll
            for (int p = 0; p < PPT; ++p) quad[p] = fmaf(zi[p], zi[p], quad[p]);
        }
        const float c0 = RL(CBASE(k) + 152);
#pragma unroll
        for (int p = 0; p < PPT; ++p) pr[p][k] = EXP2F(c0 - quad[p]);
    }

#pragma unroll
    for (int pp = 0; pp < PPT; ++pp) {
        float ss = 0.0f;
#pragma unroll
        for (int k = 0; k < KK; ++k) ss = fmaf(pr[pp][k], pr[pp][k], ss);
        const float inv = rsqrtf(fmaxf(ss, 1e-12f));

        float4* op = reinterpret_cast<float4*>(out + (base + pp * 64) * 24);
        const float* xr = xv[pp];
        op[0] = make_float4(xr[0],  xr[1],  xr[2],  xr[3]);
        op[1] = make_float4(xr[4],  xr[5],  xr[6],  xr[7]);
        op[2] = make_float4(xr[8],  xr[9],  xr[10], xr[11]);
        op[3] = make_float4(xr[12], xr[13], xr[14], xr[15]);
        op[4] = make_float4(pr[pp][0] * inv, pr[pp][1] * inv, pr[pp][2] * inv, pr[pp][3] * inv);
        op[5] = make_float4(pr[pp][4] * inv, pr[pp][5] * inv, pr[pp][6] * inv, pr[pp][7] * inv);
    }
}

extern "C" void kernel_launch(void* const* d_in, const int* in_sizes, int n_in,
                              void* d_out, int out_size, void* d_ws, size_t ws_size,
                              hipStream_t stream) {
    const float* x    = (const float*)d_in[0];   // [B,H,W,C] fp32
    const float* mean = (const float*)d_in[1];   // [K,C] fp32
    const float* st   = (const float*)d_in[2];   // [K,C,C] fp32
    float* out = (float*)d_out;                  // [B,H,W,C+K] fp32

    fuzzy_kernel<<<NPIX / (TPB * PPT), TPB, 0, stream>>>(x, mean, st, out);
}

// Round 4
// 28.168 us; speedup vs baseline: 4.0082x; 4.0082x over previous
//
#include <hip/hip_runtime.h>
#include <math.h>

#define NPIX (8 * 256 * 256)   // B*H*W
#define CC 16                  // C
#define KK 8                   // K classes
#define TPB 256                // 4 waves
#define NTILES 8               // 16-pixel tiles per wave -> 512 px/block

typedef __attribute__((ext_vector_type(8))) short short8;  // 8 bf16 (4 VGPRs)
typedef __attribute__((ext_vector_type(4))) float f32x4;

#if __has_builtin(__builtin_amdgcn_exp2f)
#define EXP2F(v) __builtin_amdgcn_exp2f(v)
#else
#define EXP2F(v) exp2f(v)
#endif

// prob_k = exp2( c0_k - sum_i z_i^2 ),  z = SC*Linv*(x - mean),  SC = sqrt(0.5*log2 e)
// Z computed by MFMA: D[row=i][col=pixel] = A(W)[i][k] * B(x)[k][pixel] + bias
// k = 2f+s: B[2f]=x_hi[f], B[2f+1]=x_lo[f]; A1=[W_hi,W_hi], A2=[W_lo,0]

__global__ __launch_bounds__(TPB) void fuzzy_kernel(const float* __restrict__ x,
                                                    const float* __restrict__ mean,
                                                    const float* __restrict__ st,
                                                    float* __restrict__ out) {
    __shared__ float linv[KK][CC][CC + 1];   // unscaled tril inverse
    __shared__ int4  a1buf[KK][64];          // A1 fragments per lane
    __shared__ int4  a2buf[KK][64];          // A2 fragments per lane
    __shared__ f32x4 bbuf[KK][64];           // bias in C-layout per lane
    __shared__ float c0buf[KK];

    const int t = threadIdx.x;

    // ---- phase A: tril inverse, one column per thread (t<128); c0 on t=128..135
    if (t < 128) {
        const int k = t >> 4, j = t & 15;
        const float* L = st + k * CC * CC;
        float col[CC];
#pragma unroll
        for (int i = 0; i < CC; ++i) {
            float s = (i == j) ? 1.0f : 0.0f;
#pragma unroll
            for (int m = 0; m < i; ++m) s = fmaf(-L[i * CC + m], col[m], s);
            col[i] = (i < j) ? 0.0f : s / L[i * CC + i];
            linv[k][i][j] = col[i];
        }
    } else if (t < 128 + KK) {
        const int k = t - 128;
        const float* L = st + k * CC * CC;
        float ld = 0.0f;
#pragma unroll
        for (int i = 0; i < CC; ++i) ld += __logf(fabsf(L[i * CC + i]));
        // -0.5*16*ln(2pi) = -14.70301653; log2(e) = 1.44269504
        c0buf[k] = (-14.70301653f - ld) * 1.44269504f;
    }
    __syncthreads();

    // ---- phase B: build fragments; 512 (class,lane) slots, 2 per thread ----
    const float SCALE = 0.8493218891f;  // sqrt(0.5*log2(e))
#pragma unroll
    for (int pass = 0; pass < 2; ++pass) {
        const int idx = t + pass * 256;
        const int k = idx >> 6, l = idx & 63;
        const int i = l & 15, g = l >> 4;   // A row = i, feature base = g*4
        int a1v[4], a2v[4];
#pragma unroll
        for (int f = 0; f < 4; ++f) {
            const float w = SCALE * linv[k][i][g * 4 + f];
            const unsigned whb = __float_as_uint(w) & 0xFFFF0000u;   // W_hi bits
            const float wl = w - __uint_as_float(whb);               // exact residual
            const unsigned hb = whb >> 16;
            a1v[f] = (int)(hb | (hb << 16));                 // [W_hi, W_hi]
            a2v[f] = (int)(__float_as_uint(wl) >> 16);       // [W_lo, 0]
        }
        a1buf[k][l] = make_int4(a1v[0], a1v[1], a1v[2], a1v[3]);
        a2buf[k][l] = make_int4(a2v[0], a2v[1], a2v[2], a2v[3]);
        f32x4 bv;
#pragma unroll
        for (int r = 0; r < 4; ++r) {
            const int row = g * 4 + r;                       // C-layout row
            float b = 0.0f;
#pragma unroll
            for (int j2 = 0; j2 < CC; ++j2) b = fmaf(linv[k][row][j2], mean[k * CC + j2], b);
            bv[r] = -b * SCALE;
        }
        bbuf[k][l] = bv;
    }
    __syncthreads();

    // ---- per-wave: hoist A fragments + c0 into registers ----
    const int lane = t & 63;
    const int wid  = t >> 6;
    short8 A1[KK], A2[KK];
    float c0v[KK];
#pragma unroll
    for (int k = 0; k < KK; ++k) {
        A1[k] = __builtin_bit_cast(short8, a1buf[k][lane]);
        A2[k] = __builtin_bit_cast(short8, a2buf[k][lane]);
        c0v[k] = c0buf[k];
    }

    // ---- main loop: 8 tiles of 16 pixels per wave ----
    const int p = lane & 15, g = lane >> 4;
    const size_t wbase = (size_t)blockIdx.x * 512 + (size_t)wid * 128;  // wave pixel base
    const float* xptr = x + wbase * CC + (size_t)(p * 16 + g * 4);      // lane's float4
    float* optr = out + (wbase + p) * 24 + g * 4;

    float4 xf0 = *(const float4*)(xptr);
    float4 xf1 = *(const float4*)(xptr + 256);

#pragma unroll
    for (int tt = 0; tt < NTILES; ++tt) {
        float4 xf2 = (tt + 2 < NTILES) ? *(const float4*)(xptr + (size_t)(tt + 2) * 256) : xf0;

        // pack B-fragment: dword f = [x_hi(low16) | x_lo(high16)]
        int bq[4];
        {
            const float xs[4] = {xf0.x, xf0.y, xf0.z, xf0.w};
#pragma unroll
            for (int f = 0; f < 4; ++f) {
                const unsigned th = __float_as_uint(xs[f]) & 0xFFFF0000u;
                const float lo = xs[f] - __uint_as_float(th);
                bq[f] = (int)((th >> 16) | (__float_as_uint(lo) & 0xFFFF0000u));
            }
        }
        const short8 B = __builtin_bit_cast(short8, make_int4(bq[0], bq[1], bq[2], bq[3]));

        f32x4 acc[KK];
#pragma unroll
        for (int k = 0; k < KK; ++k) acc[k] = bbuf[k][lane];            // bias init
#pragma unroll
        for (int k = 0; k < KK; ++k)
            acc[k] = __builtin_amdgcn_mfma_f32_16x16x32_bf16(A1[k], B, acc[k], 0, 0, 0);
#pragma unroll
        for (int k = 0; k < KK; ++k)
            acc[k] = __builtin_amdgcn_mfma_f32_16x16x32_bf16(A2[k], B, acc[k], 0, 0, 0);

        // quad = sum_i z^2 : 4 regs + butterfly over lane groups
        float pr[KK];
#pragma unroll
        for (int k = 0; k < KK; ++k) {
            float s = acc[k][0] * acc[k][0];
            s = fmaf(acc[k][1], acc[k][1], s);
            s = fmaf(acc[k][2], acc[k][2], s);
            s = fmaf(acc[k][3], acc[k][3], s);
            s += __shfl_xor(s, 16, 64);
            s += __shfl_xor(s, 32, 64);
            pr[k] = EXP2F(c0v[k] - s);
        }
        float ss = 0.0f;
#pragma unroll
        for (int k = 0; k < KK; ++k) ss = fmaf(pr[k], pr[k], ss);
        const float inv = rsqrtf(fmaxf(ss, 1e-12f));

        float* o = optr + (size_t)tt * 384;   // 16 px * 24 floats
        *(float4*)o = xf0;                    // x passthrough (cols g*4..+4)
        if (lane < 32) {                      // g==0 -> cols 16..19, g==1 -> cols 20..23
            float4 pv;
            if (g == 0) pv = make_float4(pr[0] * inv, pr[1] * inv, pr[2] * inv, pr[3] * inv);
            else        pv = make_float4(pr[4] * inv, pr[5] * inv, pr[6] * inv, pr[7] * inv);
            *(float4*)(o + 16) = pv;
        }

        xf0 = xf1; xf1 = xf2;
    }
}

extern "C" void kernel_launch(void* const* d_in, const int* in_sizes, int n_in,
                              void* d_out, int out_size, void* d_ws, size_t ws_size,
                              hipStream_t stream) {
    const float* x    = (const float*)d_in[0];   // [B,H,W,C] fp32
    const float* mean = (const float*)d_in[1];   // [K,C] fp32
    const float* st   = (const float*)d_in[2];   // [K,C,C] fp32
    float* out = (float*)d_out;                  // [B,H,W,C+K] fp32

    fuzzy_kernel<<<NPIX / 512, TPB, 0, stream>>>(x, mean, st, out);
}

// Round 5
// 23.964 us; speedup vs baseline: 4.7114x; 1.1754x over previous
//
#include <hip/hip_runtime.h>
#include <math.h>

#define NPIX (8 * 256 * 256)   // B*H*W
#define CC 16                  // C
#define KK 8                   // K classes
#define TPB 256                // 4 waves
#define NTILES 16              // 16-pixel tiles per wave -> 1024 px/block

typedef __attribute__((ext_vector_type(8))) short short8;  // 8 bf16 (4 VGPRs)
typedef __attribute__((ext_vector_type(4))) float f32x4;

#if __has_builtin(__builtin_amdgcn_exp2f)
#define EXP2F(v) __builtin_amdgcn_exp2f(v)
#else
#define EXP2F(v) exp2f(v)
#endif

// Cross-lane fold s[l] += s[l^16] (all lanes), via gfx950 VALU permlane; LDS-pipe-free.
__device__ __forceinline__ float fold16(float s) {
#if __has_builtin(__builtin_amdgcn_permlane16_swap)
    auto r = __builtin_amdgcn_permlane16_swap(__float_as_uint(s), __float_as_uint(s), false, false);
    return __uint_as_float(r[0]) + __uint_as_float(r[1]);
#else
    return s + __shfl_xor(s, 16, 64);
#endif
}
__device__ __forceinline__ float fold32(float s) {
#if __has_builtin(__builtin_amdgcn_permlane32_swap)
    auto r = __builtin_amdgcn_permlane32_swap(__float_as_uint(s), __float_as_uint(s), false, false);
    return __uint_as_float(r[0]) + __uint_as_float(r[1]);
#else
    return s + __shfl_xor(s, 32, 64);
#endif
}

// prob_k = exp2( c0_k - sum_i z_i^2 ),  z = SC*Linv*(x - mean),  SC = sqrt(0.5*log2 e)
// Z via MFMA: D[row=i][col=pixel] = A(W)[i][k] * B(x)[k][pixel] + bias
// k = 2f+s: B[2f]=x_hi[f], B[2f+1]=x_lo[f]; A1=[W_hi,W_hi], A2=[W_lo,0]

__global__ __launch_bounds__(TPB, 2) void fuzzy_kernel(const float* __restrict__ x,
                                                       const float* __restrict__ mean,
                                                       const float* __restrict__ st,
                                                       float* __restrict__ out) {
    __shared__ float linv[KK][CC][CC + 1];   // unscaled tril inverse
    __shared__ int4  a1buf[KK][64];          // A1 fragments per lane
    __shared__ int4  a2buf[KK][64];          // A2 fragments per lane
    __shared__ f32x4 bbuf[KK][64];           // bias in C-layout per lane
    __shared__ float c0buf[KK];

    const int t = threadIdx.x;

    // ---- phase A: tril inverse, one column per thread (t<128); c0 on t=128..135
    if (t < 128) {
        const int k = t >> 4, j = t & 15;
        const float* L = st + k * CC * CC;
        float col[CC];
#pragma unroll
        for (int i = 0; i < CC; ++i) {
            float s = (i == j) ? 1.0f : 0.0f;
#pragma unroll
            for (int m = 0; m < i; ++m) s = fmaf(-L[i * CC + m], col[m], s);
            col[i] = (i < j) ? 0.0f : s / L[i * CC + i];
            linv[k][i][j] = col[i];
        }
    } else if (t < 128 + KK) {
        const int k = t - 128;
        const float* L = st + k * CC * CC;
        float ld = 0.0f;
#pragma unroll
        for (int i = 0; i < CC; ++i) ld += __logf(fabsf(L[i * CC + i]));
        // -0.5*16*ln(2pi) = -14.70301653; log2(e) = 1.44269504
        c0buf[k] = (-14.70301653f - ld) * 1.44269504f;
    }
    __syncthreads();

    // ---- phase B: build fragments; 512 (class,lane) slots, 2 per thread ----
    const float SCALE = 0.8493218891f;  // sqrt(0.5*log2(e))
#pragma unroll
    for (int pass = 0; pass < 2; ++pass) {
        const int idx = t + pass * 256;
        const int k = idx >> 6, l = idx & 63;
        const int i = l & 15, g = l >> 4;   // A row = i, feature base = g*4
        int a1v[4], a2v[4];
#pragma unroll
        for (int f = 0; f < 4; ++f) {
            const float w = SCALE * linv[k][i][g * 4 + f];
            const unsigned whb = __float_as_uint(w) & 0xFFFF0000u;   // W_hi bits
            const float wl = w - __uint_as_float(whb);               // exact residual
            const unsigned hb = whb >> 16;
            a1v[f] = (int)(hb | (hb << 16));                 // [W_hi, W_hi]
            a2v[f] = (int)(__float_as_uint(wl) >> 16);       // [W_lo, 0]
        }
        a1buf[k][l] = make_int4(a1v[0], a1v[1], a1v[2], a1v[3]);
        a2buf[k][l] = make_int4(a2v[0], a2v[1], a2v[2], a2v[3]);
        f32x4 bv;
#pragma unroll
        for (int r = 0; r < 4; ++r) {
            const int row = g * 4 + r;                       // C-layout row
            float b = 0.0f;
#pragma unroll
            for (int j2 = 0; j2 < CC; ++j2) b = fmaf(linv[k][row][j2], mean[k * CC + j2], b);
            bv[r] = -b * SCALE;
        }
        bbuf[k][l] = bv;
    }
    __syncthreads();

    // ---- per-wave: hoist A fragments + bias + c0 into registers ----
    const int lane = t & 63;
    const int wid  = t >> 6;
    short8 A1[KK], A2[KK];
    f32x4 bias[KK];
    float c0v[KK];
#pragma unroll
    for (int k = 0; k < KK; ++k) {
        A1[k]   = __builtin_bit_cast(short8, a1buf[k][lane]);
        A2[k]   = __builtin_bit_cast(short8, a2buf[k][lane]);
        bias[k] = bbuf[k][lane];
        c0v[k]  = c0buf[k];
    }

    // ---- main loop: 16 tiles of 16 pixels per wave; zero LDS ops inside ----
    const int p = lane & 15, g = lane >> 4;
    const size_t wbase = (size_t)blockIdx.x * 1024 + (size_t)wid * 256;  // wave pixel base
    const float* xptr = x + wbase * CC + (size_t)(p * 16 + g * 4);       // lane's float4
    float* optr = out + (wbase + p) * 24 + g * 4;

    float4 xf0 = *(const float4*)(xptr);
    float4 xf1 = *(const float4*)(xptr + 256);

#pragma unroll
    for (int tt = 0; tt < NTILES; ++tt) {
        float4 xf2 = (tt + 2 < NTILES) ? *(const float4*)(xptr + (size_t)(tt + 2) * 256) : xf0;

        // pack B-fragment: dword f = [x_hi(low16) | x_lo(high16)]
        int bq[4];
        {
            const float xs[4] = {xf0.x, xf0.y, xf0.z, xf0.w};
#pragma unroll
            for (int f = 0; f < 4; ++f) {
                const unsigned th = __float_as_uint(xs[f]) & 0xFFFF0000u;
                const float lo = xs[f] - __uint_as_float(th);
                bq[f] = (int)((th >> 16) | (__float_as_uint(lo) & 0xFFFF0000u));
            }
        }
        const short8 B = __builtin_bit_cast(short8, make_int4(bq[0], bq[1], bq[2], bq[3]));

        f32x4 acc[KK];
#pragma unroll
        for (int k = 0; k < KK; ++k) acc[k] = bias[k];                  // reg-resident init
#pragma unroll
        for (int k = 0; k < KK; ++k)
            acc[k] = __builtin_amdgcn_mfma_f32_16x16x32_bf16(A1[k], B, acc[k], 0, 0, 0);
#pragma unroll
        for (int k = 0; k < KK; ++k)
            acc[k] = __builtin_amdgcn_mfma_f32_16x16x32_bf16(A2[k], B, acc[k], 0, 0, 0);

        // quad = sum_i z^2 : 4 regs + VALU permlane folds (no LDS pipe)
        float pr[KK];
#pragma unroll
        for (int k = 0; k < KK; ++k) {
            float s = acc[k][0] * acc[k][0];
            s = fmaf(acc[k][1], acc[k][1], s);
            s = fmaf(acc[k][2], acc[k][2], s);
            s = fmaf(acc[k][3], acc[k][3], s);
            s = fold32(fold16(s));
            pr[k] = EXP2F(c0v[k] - s);
        }
        float ss = 0.0f;
#pragma unroll
        for (int k = 0; k < KK; ++k) ss = fmaf(pr[k], pr[k], ss);
        const float inv = rsqrtf(fmaxf(ss, 1e-12f));

        float* o = optr + (size_t)tt * 384;   // 16 px * 24 floats
        *(float4*)o = xf0;                    // x passthrough (cols g*4..+4)
        if (lane < 32) {                      // g==0 -> cols 16..19, g==1 -> cols 20..23
            float4 pv;
            if (g == 0) pv = make_float4(pr[0] * inv, pr[1] * inv, pr[2] * inv, pr[3] * inv);
            else        pv = make_float4(pr[4] * inv, pr[5] * inv, pr[6] * inv, pr[7] * inv);
            *(float4*)(o + 16) = pv;
        }

        xf0 = xf1; xf1 = xf2;
    }
}

extern "C" void kernel_launch(void* const* d_in, const int* in_sizes, int n_in,
                              void* d_out, int out_size, void* d_ws, size_t ws_size,
                              hipStream_t stream) {
    const float* x    = (const float*)d_in[0];   // [B,H,W,C] fp32
    const float* mean = (const float*)d_in[1];   // [K,C] fp32
    const float* st   = (const float*)d_in[2];   // [K,C,C] fp32
    float* out = (float*)d_out;                  // [B,H,W,C+K] fp32

    fuzzy_kernel<<<NPIX / 1024, TPB, 0, stream>>>(x, mean, st, out);
}